// Round 23
// baseline (100.894 us; speedup 1.0000x reference)
//
#include <hip/hip_runtime.h>
#include <hip/hip_fp16.h>
#include <math.h>

#define BATCH   16384
#define IMGPIX  784
#define NTOT    (BATCH * IMGPIX)
#define NSLOT   64
#define SLOTSTR 8
#define STAGE_DBL (NSLOT * SLOTSTR)
// Tiled fp16 layout: [G=img/8][r=0..27][c4=0..6][i=img%8][px=0..3]
#define TROW 224
#define TGRP 6272
// fp16 conv passes: 7 strips x 4 output rows; grid = 2048G x 7s / 4 waves per block
#define CONVBLK 3584

typedef _Float16 half8 __attribute__((ext_vector_type(8)));
typedef float f32x4 __attribute__((ext_vector_type(4)));

struct __align__(8) h4 { __half2 lo, hi; };
__device__ __forceinline__ h4 f4_to_h4(float4 v) {
    h4 r; r.lo = __floats2half2_rn(v.x, v.y); r.hi = __floats2half2_rn(v.z, v.w); return r;
}
__device__ __forceinline__ float4 h4_to_f4(h4 p) {
    float2 a = __half22float2(p.lo), b = __half22float2(p.hi);
    return make_float4(a.x, a.y, b.x, b.y);
}
#define ZERO4 make_float4(0.f, 0.f, 0.f, 0.f)

// ---------------- stats ----------------
__device__ __forceinline__ void block_stats_atomic(double lsum, double lsq, double* slot) {
    __shared__ double red[4][2];
    #pragma unroll
    for (int off = 32; off >= 1; off >>= 1) {
        lsum += __shfl_down(lsum, off, 64);
        lsq  += __shfl_down(lsq,  off, 64);
    }
    const int lane = threadIdx.x & 63;
    const int w    = threadIdx.x >> 6;
    if (lane == 0) { red[w][0] = lsum; red[w][1] = lsq; }
    __syncthreads();
    if (threadIdx.x == 0) {
        double ts = (red[0][0] + red[1][0]) + (red[2][0] + red[3][0]);
        double tq = (red[0][1] + red[1][1]) + (red[2][1] + red[3][1]);
        atomicAdd(&slot[0], ts);
        atomicAdd(&slot[1], tq);
    }
}

__device__ __forceinline__ float2 stats_ab(const double* __restrict__ stats_in,
                                           float gamma, float beta) {
    int lane = threadIdx.x & 63;
    double s = stats_in[lane * SLOTSTR];
    double q = stats_in[lane * SLOTSTR + 1];
    #pragma unroll
    for (int off = 32; off >= 1; off >>= 1) {
        s += __shfl_down(s, off, 64);
        q += __shfl_down(q, off, 64);
    }
    s = __shfl(s, 0, 64);
    q = __shfl(q, 0, 64);
    const double INV_N = 1.0 / (double)NTOT;
    double mean = s * INV_N;
    double var  = q * INV_N - mean * mean;
    float rstd = 1.0f / sqrtf((float)var + 1e-5f);
    float a  = gamma * rstd;
    float bb = beta - (float)mean * a;
    return make_float2(a, bb);
}

// ---------------- conv core ----------------
__device__ __forceinline__ float4 hrow(float wl, float wc, float wr,
                                       float L, float4 v, float R) {
    float4 h;
    h.x = fmaf(wl, L,   fmaf(wc, v.x, wr * v.y));
    h.y = fmaf(wl, v.x, fmaf(wc, v.y, wr * v.z));
    h.z = fmaf(wl, v.y, fmaf(wc, v.z, wr * v.w));
    h.w = fmaf(wl, v.z, fmaf(wc, v.w, wr * R));
    return h;
}

__device__ __forceinline__ void emit_row(__half* dst, int r, float4 o, float mf,
                                         double& lsum, double& lsq, bool act) {
    if (act) *(h4*)(dst + r * TROW) = f4_to_h4(o);
    float s4 = (o.x + o.y) + (o.z + o.w);
    float q4 = fmaf(o.x, o.x, fmaf(o.y, o.y, fmaf(o.z, o.z, o.w * o.w)));
    lsum += (double)(mf * s4);
    lsq  += (double)(mf * q4);
}

#define LANE_SETUP()                                                          \
    const int t = threadIdx.x;                                                \
    const int lane = t & 63;                                                  \
    const int widx = t >> 6;                                                  \
    const int c4   = lane & 7;                                                \
    const bool act = (c4 < 7);                                                \
    const float mf = act ? 1.f : 0.f;                                         \
    const int c4c  = c4 < 7 ? c4 : 6;                                         \
    const int task = blockIdx.x * 4 + widx;   /* 0..14335 */                  \
    const int s    = task >> 11;              /* strip 0..6 */                \
    const int G    = task & 2047;             /* 8-image group */             \
    const int r0   = s * 4;                                                   \
    const int rtop = (r0 > 0)  ? (r0 - 1) : 0;                                \
    const int rbot = (r0 < 24) ? (r0 + 4) : 27;                               \
    const int i8   = lane >> 3;                                               \
    const size_t tbR   = (size_t)G * TGRP + c4c * 32 + i8 * 4;                \
    const size_t tbW   = (size_t)G * TGRP + c4  * 32 + i8 * 4;

#define CONV_STEP(k, v)                                                       \
    {                                                                         \
        float L = __shfl_up((v).w, 1, 64);  if (c4 == 0) L = 0.f;             \
        float R = __shfl_down((v).x, 1, 64); if (c4 == 6) R = 0.f;            \
        float4 h2 = hrow(w9[6], w9[7], w9[8], L, (v), R);                     \
        float4 h1 = hrow(w9[3], w9[4], w9[5], L, (v), R);                     \
        float4 h0 = hrow(w9[0], w9[1], w9[2], L, (v), R);                     \
        accA.x += h2.x; accA.y += h2.y; accA.z += h2.z; accA.w += h2.w;       \
        if ((k) >= 2) emit_row(dst, r0 + (k) - 2, accA, mf, lsum, lsq, act);  \
        accA.x = accB.x + h1.x; accA.y = accB.y + h1.y;                       \
        accA.z = accB.z + h1.z; accA.w = accB.w + h1.w;                       \
        accB = h0;                                                            \
    }

#define HALO_ZERO(k, v)                                                       \
    if ((k) == 0 && r0 == 0)  (v) = ZERO4;                                    \
    if ((k) == 5 && r0 == 24) (v) = ZERO4;

// Pass 0: x16 = fp16(x) tiled (pure conversion; coalesced both sides via LDS).
// Bpack/qkpad builders distributed over blocks 0..56.
__global__ __launch_bounds__(256, 8) void k_x16(const float* __restrict__ in,
        __half* __restrict__ x16_out,
        const float* __restrict__ fc_w, const float* __restrict__ fc_b,
        const float* __restrict__ theta, const float* __restrict__ alpha_p,
        __half* __restrict__ Bpack, float* __restrict__ qkpad)
{
    __shared__ __half xs[28 * TROW];           // 12.25 KB, tiled
    const int t = threadIdx.x;
    const int G = blockIdx.x;

    // Phase A: coalesced f32 read -> tiled scatter into LDS
    const float4* xg = (const float4*)(in + (size_t)G * 8 * IMGPIX);
    for (int f = t; f < 1568; f += 256) {      // f = il*196 + (r*7+c4)
        float4 v = xg[f];
        int il = f / 196;
        int p  = f - il * 196;
        int r  = p / 7;
        int c4s = p - r * 7;
        *(h4*)(&xs[r * TROW + c4s * 32 + il * 4]) = f4_to_h4(v);
    }
    __syncthreads();

    // Phase B: tiled-contiguous writeback (fully coalesced)
    __half* xo = x16_out + (size_t)G * TGRP;
    for (int f = t; f < 1568; f += 256)
        *(h4*)(xo + f * 4) = *(const h4*)(&xs[f * 4]);

    // ---- distributed builder ----
    if (blockIdx.x < 56) {
        const int idx = blockIdx.x * 256 + t;  // 0..14335 = 28*512
        const int r = idx >> 9;
        const int l = (idx >> 3) & 63;
        const int j = idx & 7;
        const int n = l & 15;                  // class (B col)
        const int c = ((l >> 4) << 3) + j;     // padded k col
        float v = 0.f;
        if (c < 28 && n < 10) v = fc_w[n * 784 + r * 28 + c];
        Bpack[idx] = __float2half(v);
    } else if (blockIdx.x == 56) {
        __shared__ float csum[10];
        if (t < 80) {
            int k = t >> 3, oct = t & 7;
            float sm = 0.f;
            #pragma unroll
            for (int i = 0; i < 25; i++) {
                int p = oct + 8 * i;
                if (p < 196) sm += fc_w[k * 784 + p * 4];
            }
            sm += __shfl_xor(sm, 1, 64);
            sm += __shfl_xor(sm, 2, 64);
            sm += __shfl_xor(sm, 4, 64);
            if (oct == 0) csum[k] = sm;
        }
        __syncthreads();
        if (t < 16) {
            float val = -1e30f;
            if (t < 10) {
                float c = 1.f;
                #pragma unroll
                for (int i = 0; i < 24; i++) c *= cosf(theta[i] * 0.5f);
                val = fmaf((1.f - alpha_p[0]) * c * c, csum[t], fc_b[t]);
            }
            qkpad[t] = val;
        }
    }
}

// Pass 1: y1 = conv(x16); stats(y1). Identical structure to k_conv_affine
// (the proven ~10us template) with identity "BN" (no scale/relu).
__global__ __launch_bounds__(256, 8) void k_conv1(const __half* __restrict__ in,
        const float* __restrict__ w, __half* __restrict__ out,
        double* __restrict__ stats_out)
{
    LANE_SETUP();
    float w9[9];
    #pragma unroll
    for (int i = 0; i < 9; i++) w9[i] = w[i];
    const __half* src = in + tbR;
    __half* dst = out + tbW;

    h4 vb[6];
    vb[0] = *(const h4*)(src + rtop * TROW);
    #pragma unroll
    for (int k = 1; k < 5; k++) vb[k] = *(const h4*)(src + (r0 - 1 + k) * TROW);
    vb[5] = *(const h4*)(src + rbot * TROW);
    __builtin_amdgcn_sched_barrier(0);

    float4 accA = ZERO4, accB = ZERO4;
    double lsum = 0.0, lsq = 0.0;
    #pragma unroll
    for (int k = 0; k < 6; k++) {
        float4 v = h4_to_f4(vb[k]);
        HALO_ZERO(k, v);                       // conv1 input = x, zero pad
        CONV_STEP(k, v);
    }
    block_stats_atomic(lsum, lsq, &stats_out[(blockIdx.x & (NSLOT - 1)) * SLOTSTR]);
}

// Pass 2/4: y = conv(relu(bn(in))); stats(y).  in/out fp16 tiled.
__global__ __launch_bounds__(256, 8) void k_conv_affine(const __half* __restrict__ in,
        const double* __restrict__ stats_in,
        const float* __restrict__ gamma, const float* __restrict__ beta,
        const float* __restrict__ w, __half* __restrict__ out, double* __restrict__ stats_out)
{
    LANE_SETUP();
    float2 ab = stats_ab(stats_in, gamma[0], beta[0]);
    float w9[9];
    #pragma unroll
    for (int i = 0; i < 9; i++) w9[i] = w[i];
    const __half* src = in + tbR;
    __half* dst = out + tbW;

    h4 vb[6];
    vb[0] = *(const h4*)(src + rtop * TROW);
    #pragma unroll
    for (int k = 1; k < 5; k++) vb[k] = *(const h4*)(src + (r0 - 1 + k) * TROW);
    vb[5] = *(const h4*)(src + rbot * TROW);
    __builtin_amdgcn_sched_barrier(0);

    float4 accA = ZERO4, accB = ZERO4;
    double lsum = 0.0, lsq = 0.0;
    #pragma unroll
    for (int k = 0; k < 6; k++) {
        float4 r4 = h4_to_f4(vb[k]);
        float4 v;
        v.x = fmaxf(fmaf(ab.x, r4.x, ab.y), 0.f);
        v.y = fmaxf(fmaf(ab.x, r4.y, ab.y), 0.f);
        v.z = fmaxf(fmaf(ab.x, r4.z, ab.y), 0.f);
        v.w = fmaxf(fmaf(ab.x, r4.w, ab.y), 0.f);
        HALO_ZERO(k, v);                   // pad AFTER activation (matches ref)
        CONV_STEP(k, v);
    }
    block_stats_atomic(lsum, lsq, &stats_out[(blockIdx.x & (NSLOT - 1)) * SLOTSTR]);
}

// Pass 3: o1 = relu(bn(y2)+x16) [stored, owned rows]; y3 = conv(o1); stats(y3)
__global__ __launch_bounds__(256, 8) void k_conv_resid(const __half* __restrict__ y2,
        const __half* __restrict__ x16, const double* __restrict__ stats_in,
        const float* __restrict__ gamma, const float* __restrict__ beta,
        const float* __restrict__ w, __half* __restrict__ y3_out,
        __half* __restrict__ o1_out, double* __restrict__ stats_out)
{
    LANE_SETUP();
    float2 ab = stats_ab(stats_in, gamma[0], beta[0]);
    float w9[9];
    #pragma unroll
    for (int i = 0; i < 9; i++) w9[i] = w[i];
    const __half* srcy = y2 + tbR;
    const __half* srcx = x16 + tbR;
    __half* dst  = y3_out + tbW;
    __half* dsto = o1_out + tbW;

    h4 yb[6], xb[6];
    yb[0] = *(const h4*)(srcy + rtop * TROW);
    xb[0] = *(const h4*)(srcx + rtop * TROW);
    #pragma unroll
    for (int k = 1; k < 5; k++) {
        yb[k] = *(const h4*)(srcy + (r0 - 1 + k) * TROW);
        xb[k] = *(const h4*)(srcx + (r0 - 1 + k) * TROW);
    }
    yb[5] = *(const h4*)(srcy + rbot * TROW);
    xb[5] = *(const h4*)(srcx + rbot * TROW);
    __builtin_amdgcn_sched_barrier(0);

    float4 accA = ZERO4, accB = ZERO4;
    double lsum = 0.0, lsq = 0.0;
    #pragma unroll
    for (int k = 0; k < 6; k++) {
        float4 r4 = h4_to_f4(yb[k]);
        float4 x4 = h4_to_f4(xb[k]);
        float4 v;
        v.x = fmaxf(fmaf(ab.x, r4.x, ab.y) + x4.x, 0.f);
        v.y = fmaxf(fmaf(ab.x, r4.y, ab.y) + x4.y, 0.f);
        v.z = fmaxf(fmaf(ab.x, r4.z, ab.y) + x4.z, 0.f);
        v.w = fmaxf(fmaf(ab.x, r4.w, ab.y) + x4.w, 0.f);
        HALO_ZERO(k, v);
        if (act && k >= 1 && k <= 4)           // owned rows only
            *(h4*)(dsto + (r0 - 1 + k) * TROW) = f4_to_h4(v);
        CONV_STEP(k, v);
    }
    block_stats_atomic(lsum, lsq, &stats_out[(blockIdx.x & (NSLOT - 1)) * SLOTSTR]);
}

// Pass 5 (MFMA): C[16384x16] = o2[16384x784pad] @ Bpack; logits/softmax.
__global__ __launch_bounds__(256, 4) void k_head_mfma(const __half* __restrict__ y4,
        const __half* __restrict__ o1, const double* __restrict__ stats_in,
        const float* __restrict__ gamma, const float* __restrict__ beta,
        const __half* __restrict__ Bpack, const float* __restrict__ qkpad,
        const float* __restrict__ alpha_p, float* __restrict__ out)
{
    __shared__ float accs[4][64][4];
    const int t    = threadIdx.x;
    const int lane = t & 63;
    const int q    = t >> 6;               // K-quarter: rows 7q..7q+6
    float2 ab = stats_ab(stats_in, gamma[0], beta[0]);

    const int m   = lane & 15;             // image within tile (A row)
    const int jg  = lane >> 4;             // k-slice group 0..3
    const int c4a = jg * 2;
    const int c4b = (jg == 3) ? 6 : (jg * 2 + 1);   // jg==3 upper: k 28-31 (B=0)
    const int G   = blockIdx.x * 2 + (m >> 3);
    const int i8  = m & 7;
    const size_t base = (size_t)G * TGRP + i8 * 4;
    const __half* ya = y4 + base;
    const __half* oa = o1 + base;

    f32x4 acc = {0.f, 0.f, 0.f, 0.f};
    #pragma unroll
    for (int rr = 0; rr < 7; rr++) {
        const int r  = q * 7 + rr;
        const int ro = r * TROW;
        h4 ylo = *(const h4*)(ya + ro + c4a * 32);
        h4 yhi = *(const h4*)(ya + ro + c4b * 32);
        h4 olo = *(const h4*)(oa + ro + c4a * 32);
        h4 ohi = *(const h4*)(oa + ro + c4b * 32);
        float4 yf0 = h4_to_f4(ylo), yf1 = h4_to_f4(yhi);
        float4 of0 = h4_to_f4(olo), of1 = h4_to_f4(ohi);
        float4 va, vb;
        va.x = fmaxf(fmaf(ab.x, yf0.x, ab.y) + of0.x, 0.f);
        va.y = fmaxf(fmaf(ab.x, yf0.y, ab.y) + of0.y, 0.f);
        va.z = fmaxf(fmaf(ab.x, yf0.z, ab.y) + of0.z, 0.f);
        va.w = fmaxf(fmaf(ab.x, yf0.w, ab.y) + of0.w, 0.f);
        vb.x = fmaxf(fmaf(ab.x, yf1.x, ab.y) + of1.x, 0.f);
        vb.y = fmaxf(fmaf(ab.x, yf1.y, ab.y) + of1.y, 0.f);
        vb.z = fmaxf(fmaf(ab.x, yf1.z, ab.y) + of1.z, 0.f);
        vb.w = fmaxf(fmaf(ab.x, yf1.w, ab.y) + of1.w, 0.f);
        union { half8 v; h4 qq[2]; } A;
        A.qq[0] = f4_to_h4(va);
        A.qq[1] = f4_to_h4(vb);
        half8 B = *(const half8*)(Bpack + (r * 64 + lane) * 8);
        acc = __builtin_amdgcn_mfma_f32_16x16x32_f16(A.v, B, acc, 0, 0, 0);
    }
    #pragma unroll
    for (int i = 0; i < 4; i++) accs[q][lane][i] = acc[i];
    __syncthreads();

    if (t < 64) {                          // wave 0 finalizes
        float c[4];
        #pragma unroll
        for (int i = 0; i < 4; i++)
            c[i] = (accs[0][lane][i] + accs[1][lane][i])
                 + (accs[2][lane][i] + accs[3][lane][i]);
        const float alpha = alpha_p[0];
        const int cls = lane & 15;
        const float qv = qkpad[cls];       // -1e30 for cls>=10
        #pragma unroll
        for (int i = 0; i < 4; i++) {
            float logit = fmaf(alpha, c[i], qv);
            float mx = logit;
            mx = fmaxf(mx, __shfl_xor(mx, 1, 64));
            mx = fmaxf(mx, __shfl_xor(mx, 2, 64));
            mx = fmaxf(mx, __shfl_xor(mx, 4, 64));
            mx = fmaxf(mx, __shfl_xor(mx, 8, 64));
            float se = __expf(logit - mx);
            se += __shfl_xor(se, 1, 64);
            se += __shfl_xor(se, 2, 64);
            se += __shfl_xor(se, 4, 64);
            se += __shfl_xor(se, 8, 64);
            float lse = mx + __logf(se);
            if (cls < 10) {
                int img = blockIdx.x * 16 + (lane >> 4) * 4 + i;  // C row = (l>>4)*4+i
                out[(size_t)img * 10 + cls] = logit - lse;
            }
        }
    }
}

extern "C" void kernel_launch(void* const* d_in, const int* in_sizes, int n_in,
                              void* d_out, int out_size, void* d_ws, size_t ws_size,
                              hipStream_t stream) {
    const float* x     = (const float*)d_in[0];
    const float* theta = (const float*)d_in[1];
    const float* r1_w1 = (const float*)d_in[2];
    const float* r1_g1 = (const float*)d_in[3];
    const float* r1_b1 = (const float*)d_in[4];
    const float* r1_w2 = (const float*)d_in[5];
    const float* r1_g2 = (const float*)d_in[6];
    const float* r1_b2 = (const float*)d_in[7];
    const float* r2_w1 = (const float*)d_in[8];
    const float* r2_g1 = (const float*)d_in[9];
    const float* r2_b1 = (const float*)d_in[10];
    const float* r2_w2 = (const float*)d_in[11];
    const float* r2_g2 = (const float*)d_in[12];
    const float* r2_b2 = (const float*)d_in[13];
    const float* fc_w  = (const float*)d_in[14];
    const float* fc_b  = (const float*)d_in[15];
    const float* alpha = (const float*)d_in[16];
    float* out = (float*)d_out;

    double* stats = (double*)d_ws;                       // 16 KB
    float*  qkpad = (float*)((char*)d_ws + 16384);       // 16 floats
    __half* Bpack = (__half*)((char*)d_ws + 16448);      // 28*512 halfs = 28 KB
    __half* bufA  = (__half*)((char*)d_ws + 65536);      // y1 then y3 (tiled)
    __half* bufB  = bufA + (size_t)NTOT;                 // y2 then y4 (tiled)
    __half* bufD  = bufB + (size_t)NTOT;                 // o1 (tiled)
    __half* bufX  = bufD + (size_t)NTOT;                 // x16 (tiled)

    double* s_y1 = stats + 0 * STAGE_DBL;
    double* s_y2 = stats + 1 * STAGE_DBL;
    double* s_y3 = stats + 2 * STAGE_DBL;
    double* s_y4 = stats + 3 * STAGE_DBL;

    hipMemsetAsync(stats, 0, 4 * STAGE_DBL * sizeof(double), stream);
    k_x16<<<2048, 256, 0, stream>>>(x, bufX, fc_w, fc_b, theta, alpha, Bpack, qkpad);
    k_conv1<<<CONVBLK, 256, 0, stream>>>(bufX, r1_w1, bufA, s_y1);
    k_conv_affine<<<CONVBLK, 256, 0, stream>>>(bufA, s_y1, r1_g1, r1_b1, r1_w2, bufB, s_y2);
    k_conv_resid<<<CONVBLK, 256, 0, stream>>>(bufB, bufX, s_y2, r1_g2, r1_b2, r2_w1, bufA, bufD, s_y3);
    k_conv_affine<<<CONVBLK, 256, 0, stream>>>(bufA, s_y3, r2_g1, r2_b1, r2_w2, bufB, s_y4);
    k_head_mfma<<<1024, 256, 0, stream>>>(bufB, bufD, s_y4, r2_g2, r2_b2,
                                          Bpack, qkpad, alpha, out);
}

// Round 24
// 88.353 us; speedup vs baseline: 1.1419x; 1.1419x over previous
//
#include <hip/hip_runtime.h>
#include <hip/hip_fp16.h>
#include <math.h>

#define BATCH   16384
#define IMGPIX  784
#define NTOT    (BATCH * IMGPIX)
#define NSLOT   64
#define SLOTSTR 8
#define STAGE_DBL (NSLOT * SLOTSTR)
// Tiled fp16 layout: [G=img/8][r=0..27][c4=0..6][i=img%8][px=0..3]
#define TROW 224
#define TGRP 6272
// 7 strips x 4 output rows; conv grid = 2048G x 7s / 4 waves per block
#define CONVBLK 3584

typedef _Float16 half8 __attribute__((ext_vector_type(8)));
typedef float f32x4 __attribute__((ext_vector_type(4)));

struct __align__(8) h4 { __half2 lo, hi; };
__device__ __forceinline__ h4 f4_to_h4(float4 v) {
    h4 r; r.lo = __floats2half2_rn(v.x, v.y); r.hi = __floats2half2_rn(v.z, v.w); return r;
}
__device__ __forceinline__ float4 h4_to_f4(h4 p) {
    float2 a = __half22float2(p.lo), b = __half22float2(p.hi);
    return make_float4(a.x, a.y, b.x, b.y);
}
#define ZERO4 make_float4(0.f, 0.f, 0.f, 0.f)

// ---------------- stats ----------------
__device__ __forceinline__ void block_stats_atomic(double lsum, double lsq, double* slot) {
    __shared__ double red[4][2];
    #pragma unroll
    for (int off = 32; off >= 1; off >>= 1) {
        lsum += __shfl_down(lsum, off, 64);
        lsq  += __shfl_down(lsq,  off, 64);
    }
    const int lane = threadIdx.x & 63;
    const int w    = threadIdx.x >> 6;
    if (lane == 0) { red[w][0] = lsum; red[w][1] = lsq; }
    __syncthreads();
    if (threadIdx.x == 0) {
        double ts = (red[0][0] + red[1][0]) + (red[2][0] + red[3][0]);
        double tq = (red[0][1] + red[1][1]) + (red[2][1] + red[3][1]);
        atomicAdd(&slot[0], ts);
        atomicAdd(&slot[1], tq);
    }
}

__device__ __forceinline__ float2 stats_ab(const double* __restrict__ stats_in,
                                           float gamma, float beta) {
    int lane = threadIdx.x & 63;
    double s = stats_in[lane * SLOTSTR];
    double q = stats_in[lane * SLOTSTR + 1];
    #pragma unroll
    for (int off = 32; off >= 1; off >>= 1) {
        s += __shfl_down(s, off, 64);
        q += __shfl_down(q, off, 64);
    }
    s = __shfl(s, 0, 64);
    q = __shfl(q, 0, 64);
    const double INV_N = 1.0 / (double)NTOT;
    double mean = s * INV_N;
    double var  = q * INV_N - mean * mean;
    float rstd = 1.0f / sqrtf((float)var + 1e-5f);
    float a  = gamma * rstd;
    float bb = beta - (float)mean * a;
    return make_float2(a, bb);
}

// ---------------- strip conv core ----------------
__device__ __forceinline__ float4 hrow(float wl, float wc, float wr,
                                       float L, float4 v, float R) {
    float4 h;
    h.x = fmaf(wl, L,   fmaf(wc, v.x, wr * v.y));
    h.y = fmaf(wl, v.x, fmaf(wc, v.y, wr * v.z));
    h.z = fmaf(wl, v.y, fmaf(wc, v.z, wr * v.w));
    h.w = fmaf(wl, v.z, fmaf(wc, v.w, wr * R));
    return h;
}

__device__ __forceinline__ void emit_row(__half* dst, int r, float4 o, float mf,
                                         double& lsum, double& lsq, bool act) {
    if (act) *(h4*)(dst + r * TROW) = f4_to_h4(o);
    float s4 = (o.x + o.y) + (o.z + o.w);
    float q4 = fmaf(o.x, o.x, fmaf(o.y, o.y, fmaf(o.z, o.z, o.w * o.w)));
    lsum += (double)(mf * s4);
    lsq  += (double)(mf * q4);
}

#define LANE_SETUP()                                                          \
    const int t = threadIdx.x;                                                \
    const int lane = t & 63;                                                  \
    const int widx = t >> 6;                                                  \
    const int c4   = lane & 7;                                                \
    const bool act = (c4 < 7);                                                \
    const float mf = act ? 1.f : 0.f;                                         \
    const int c4c  = c4 < 7 ? c4 : 6;                                         \
    const int task = blockIdx.x * 4 + widx;   /* 0..14335 */                  \
    const int s    = task >> 11;              /* strip 0..6 */                \
    const int G    = task & 2047;             /* 8-image group */             \
    const int r0   = s * 4;                                                   \
    const int rtop = (r0 > 0)  ? (r0 - 1) : 0;                                \
    const int rbot = (r0 < 24) ? (r0 + 4) : 27;                               \
    const int i8   = lane >> 3;                                               \
    const int img  = G * 8 + i8;                                              \
    const size_t xbase = (size_t)img * IMGPIX + c4c * 4;                      \
    const size_t tbR   = (size_t)G * TGRP + c4c * 32 + i8 * 4;                \
    const size_t tbW   = (size_t)G * TGRP + c4  * 32 + i8 * 4;

#define CONV_STEP(k, v)                                                       \
    {                                                                         \
        float L = __shfl_up((v).w, 1, 64);  if (c4 == 0) L = 0.f;             \
        float R = __shfl_down((v).x, 1, 64); if (c4 == 6) R = 0.f;            \
        float4 h2 = hrow(w9[6], w9[7], w9[8], L, (v), R);                     \
        float4 h1 = hrow(w9[3], w9[4], w9[5], L, (v), R);                     \
        float4 h0 = hrow(w9[0], w9[1], w9[2], L, (v), R);                     \
        accA.x += h2.x; accA.y += h2.y; accA.z += h2.z; accA.w += h2.w;       \
        if ((k) >= 2) emit_row(dst, r0 + (k) - 2, accA, mf, lsum, lsq, act);  \
        accA.x = accB.x + h1.x; accA.y = accB.y + h1.y;                       \
        accA.z = accB.z + h1.z; accA.w = accB.w + h1.w;                       \
        accB = h0;                                                            \
    }

#define HALO_ZERO(k, v)                                                       \
    if ((k) == 0 && r0 == 0)  (v) = ZERO4;                                    \
    if ((k) == 5 && r0 == 24) (v) = ZERO4;

// Pass 1: y1 = conv(x); stats(y1); x16 = fp16(x) tiled.
// launch_bounds(256,2): VGPR cap 256 (was 32!) so the 6 float4 x-loads can
// stay in flight — r23 isolated the x-streamer's 40us floor as MLP-starvation.
// Bpack built by blocks 0..55 (one elem/thread); qkpad by block 56.
__global__ __launch_bounds__(256, 2) void k_conv_plain(const float* __restrict__ in,
        const float* __restrict__ w, __half* __restrict__ out,
        __half* __restrict__ x16_out, double* __restrict__ stats_out,
        const float* __restrict__ fc_w, const float* __restrict__ fc_b,
        const float* __restrict__ theta, const float* __restrict__ alpha_p,
        __half* __restrict__ Bpack, float* __restrict__ qkpad)
{
    LANE_SETUP();
    float w9[9];
    #pragma unroll
    for (int i = 0; i < 9; i++) w9[i] = w[i];
    const float* src = in + xbase;
    __half* dst  = out + tbW;
    __half* dstx = x16_out + tbW;

    float4 vb[6];
    vb[0] = *(const float4*)(src + rtop * 28);
    #pragma unroll
    for (int k = 1; k < 5; k++) vb[k] = *(const float4*)(src + (r0 - 1 + k) * 28);
    vb[5] = *(const float4*)(src + rbot * 28);
    __builtin_amdgcn_sched_barrier(0);

    float4 accA = ZERO4, accB = ZERO4;
    double lsum = 0.0, lsq = 0.0;
    #pragma unroll
    for (int k = 0; k < 6; k++) {
        float4 v = vb[k];
        if (act && k >= 1 && k <= 4)           // owned rows: raw x copy
            *(h4*)(dstx + (r0 - 1 + k) * TROW) = f4_to_h4(vb[k]);
        HALO_ZERO(k, v);
        CONV_STEP(k, v);
    }
    block_stats_atomic(lsum, lsq, &stats_out[(blockIdx.x & (NSLOT - 1)) * SLOTSTR]);

    // ---- distributed builder (gen-0 blocks, hidden) ----
    if (blockIdx.x < 56) {
        const int idx = blockIdx.x * 256 + t;  // 0..14335 = 28*512
        const int r = idx >> 9;
        const int l = (idx >> 3) & 63;
        const int j = idx & 7;
        const int n = l & 15;                  // class (B col)
        const int c = ((l >> 4) << 3) + j;     // padded k col
        float v = 0.f;
        if (c < 28 && n < 10) v = fc_w[n * 784 + r * 28 + c];
        Bpack[idx] = __float2half(v);
    } else if (blockIdx.x == 56) {
        __shared__ float csum[10];
        if (t < 80) {
            int k = t >> 3, oct = t & 7;
            float sm = 0.f;
            #pragma unroll
            for (int i = 0; i < 25; i++) {
                int p = oct + 8 * i;
                if (p < 196) sm += fc_w[k * 784 + p * 4];
            }
            sm += __shfl_xor(sm, 1, 64);
            sm += __shfl_xor(sm, 2, 64);
            sm += __shfl_xor(sm, 4, 64);
            if (oct == 0) csum[k] = sm;
        }
        __syncthreads();
        if (t < 16) {
            float val = -1e30f;
            if (t < 10) {
                float c = 1.f;
                #pragma unroll
                for (int i = 0; i < 24; i++) c *= cosf(theta[i] * 0.5f);
                val = fmaf((1.f - alpha_p[0]) * c * c, csum[t], fc_b[t]);
            }
            qkpad[t] = val;
        }
    }
}

// Pass 2/4: y = conv(relu(bn(in))); stats(y).  in/out fp16 tiled.
__global__ __launch_bounds__(256, 8) void k_conv_affine(const __half* __restrict__ in,
        const double* __restrict__ stats_in,
        const float* __restrict__ gamma, const float* __restrict__ beta,
        const float* __restrict__ w, __half* __restrict__ out, double* __restrict__ stats_out)
{
    LANE_SETUP();
    float2 ab = stats_ab(stats_in, gamma[0], beta[0]);
    float w9[9];
    #pragma unroll
    for (int i = 0; i < 9; i++) w9[i] = w[i];
    const __half* src = in + tbR;
    __half* dst = out + tbW;

    h4 vb[6];
    vb[0] = *(const h4*)(src + rtop * TROW);
    #pragma unroll
    for (int k = 1; k < 5; k++) vb[k] = *(const h4*)(src + (r0 - 1 + k) * TROW);
    vb[5] = *(const h4*)(src + rbot * TROW);
    __builtin_amdgcn_sched_barrier(0);

    float4 accA = ZERO4, accB = ZERO4;
    double lsum = 0.0, lsq = 0.0;
    #pragma unroll
    for (int k = 0; k < 6; k++) {
        float4 r4 = h4_to_f4(vb[k]);
        float4 v;
        v.x = fmaxf(fmaf(ab.x, r4.x, ab.y), 0.f);
        v.y = fmaxf(fmaf(ab.x, r4.y, ab.y), 0.f);
        v.z = fmaxf(fmaf(ab.x, r4.z, ab.y), 0.f);
        v.w = fmaxf(fmaf(ab.x, r4.w, ab.y), 0.f);
        HALO_ZERO(k, v);                   // pad AFTER activation (matches ref)
        CONV_STEP(k, v);
    }
    block_stats_atomic(lsum, lsq, &stats_out[(blockIdx.x & (NSLOT - 1)) * SLOTSTR]);
}

// Pass 3: o1 = relu(bn(y2)+x16) [stored, owned rows]; y3 = conv(o1); stats(y3)
__global__ __launch_bounds__(256, 8) void k_conv_resid(const __half* __restrict__ y2,
        const __half* __restrict__ x16, const double* __restrict__ stats_in,
        const float* __restrict__ gamma, const float* __restrict__ beta,
        const float* __restrict__ w, __half* __restrict__ y3_out,
        __half* __restrict__ o1_out, double* __restrict__ stats_out)
{
    LANE_SETUP();
    float2 ab = stats_ab(stats_in, gamma[0], beta[0]);
    float w9[9];
    #pragma unroll
    for (int i = 0; i < 9; i++) w9[i] = w[i];
    const __half* srcy = y2 + tbR;
    const __half* srcx = x16 + tbR;
    __half* dst  = y3_out + tbW;
    __half* dsto = o1_out + tbW;

    h4 yb[6], xb[6];
    yb[0] = *(const h4*)(srcy + rtop * TROW);
    xb[0] = *(const h4*)(srcx + rtop * TROW);
    #pragma unroll
    for (int k = 1; k < 5; k++) {
        yb[k] = *(const h4*)(srcy + (r0 - 1 + k) * TROW);
        xb[k] = *(const h4*)(srcx + (r0 - 1 + k) * TROW);
    }
    yb[5] = *(const h4*)(srcy + rbot * TROW);
    xb[5] = *(const h4*)(srcx + rbot * TROW);
    __builtin_amdgcn_sched_barrier(0);

    float4 accA = ZERO4, accB = ZERO4;
    double lsum = 0.0, lsq = 0.0;
    #pragma unroll
    for (int k = 0; k < 6; k++) {
        float4 r4 = h4_to_f4(yb[k]);
        float4 x4 = h4_to_f4(xb[k]);
        float4 v;
        v.x = fmaxf(fmaf(ab.x, r4.x, ab.y) + x4.x, 0.f);
        v.y = fmaxf(fmaf(ab.x, r4.y, ab.y) + x4.y, 0.f);
        v.z = fmaxf(fmaf(ab.x, r4.z, ab.y) + x4.z, 0.f);
        v.w = fmaxf(fmaf(ab.x, r4.w, ab.y) + x4.w, 0.f);
        HALO_ZERO(k, v);
        if (act && k >= 1 && k <= 4)           // owned rows only
            *(h4*)(dsto + (r0 - 1 + k) * TROW) = f4_to_h4(v);
        CONV_STEP(k, v);
    }
    block_stats_atomic(lsum, lsq, &stats_out[(blockIdx.x & (NSLOT - 1)) * SLOTSTR]);
}

// Pass 5 (MFMA): C[16384x16] = o2[16384x784pad] @ Bpack; logits/softmax.
__global__ __launch_bounds__(256, 4) void k_head_mfma(const __half* __restrict__ y4,
        const __half* __restrict__ o1, const double* __restrict__ stats_in,
        const float* __restrict__ gamma, const float* __restrict__ beta,
        const __half* __restrict__ Bpack, const float* __restrict__ qkpad,
        const float* __restrict__ alpha_p, float* __restrict__ out)
{
    __shared__ float accs[4][64][4];
    const int t    = threadIdx.x;
    const int lane = t & 63;
    const int q    = t >> 6;               // K-quarter: rows 7q..7q+6
    float2 ab = stats_ab(stats_in, gamma[0], beta[0]);

    const int m   = lane & 15;             // image within tile (A row)
    const int jg  = lane >> 4;             // k-slice group 0..3
    const int c4a = jg * 2;
    const int c4b = (jg == 3) ? 6 : (jg * 2 + 1);   // jg==3 upper: k 28-31 (B=0)
    const int G   = blockIdx.x * 2 + (m >> 3);
    const int i8  = m & 7;
    const size_t base = (size_t)G * TGRP + i8 * 4;
    const __half* ya = y4 + base;
    const __half* oa = o1 + base;

    f32x4 acc = {0.f, 0.f, 0.f, 0.f};
    #pragma unroll
    for (int rr = 0; rr < 7; rr++) {
        const int r  = q * 7 + rr;
        const int ro = r * TROW;
        h4 ylo = *(const h4*)(ya + ro + c4a * 32);
        h4 yhi = *(const h4*)(ya + ro + c4b * 32);
        h4 olo = *(const h4*)(oa + ro + c4a * 32);
        h4 ohi = *(const h4*)(oa + ro + c4b * 32);
        float4 yf0 = h4_to_f4(ylo), yf1 = h4_to_f4(yhi);
        float4 of0 = h4_to_f4(olo), of1 = h4_to_f4(ohi);
        float4 va, vb;
        va.x = fmaxf(fmaf(ab.x, yf0.x, ab.y) + of0.x, 0.f);
        va.y = fmaxf(fmaf(ab.x, yf0.y, ab.y) + of0.y, 0.f);
        va.z = fmaxf(fmaf(ab.x, yf0.z, ab.y) + of0.z, 0.f);
        va.w = fmaxf(fmaf(ab.x, yf0.w, ab.y) + of0.w, 0.f);
        vb.x = fmaxf(fmaf(ab.x, yf1.x, ab.y) + of1.x, 0.f);
        vb.y = fmaxf(fmaf(ab.x, yf1.y, ab.y) + of1.y, 0.f);
        vb.z = fmaxf(fmaf(ab.x, yf1.z, ab.y) + of1.z, 0.f);
        vb.w = fmaxf(fmaf(ab.x, yf1.w, ab.y) + of1.w, 0.f);
        union { half8 v; h4 qq[2]; } A;
        A.qq[0] = f4_to_h4(va);
        A.qq[1] = f4_to_h4(vb);
        half8 B = *(const half8*)(Bpack + (r * 64 + lane) * 8);
        acc = __builtin_amdgcn_mfma_f32_16x16x32_f16(A.v, B, acc, 0, 0, 0);
    }
    #pragma unroll
    for (int i = 0; i < 4; i++) accs[q][lane][i] = acc[i];
    __syncthreads();

    if (t < 64) {                          // wave 0 finalizes
        float c[4];
        #pragma unroll
        for (int i = 0; i < 4; i++)
            c[i] = (accs[0][lane][i] + accs[1][lane][i])
                 + (accs[2][lane][i] + accs[3][lane][i]);
        const float alpha = alpha_p[0];
        const int cls = lane & 15;
        const float qv = qkpad[cls];       // -1e30 for cls>=10
        #pragma unroll
        for (int i = 0; i < 4; i++) {
            float logit = fmaf(alpha, c[i], qv);
            float mx = logit;
            mx = fmaxf(mx, __shfl_xor(mx, 1, 64));
            mx = fmaxf(mx, __shfl_xor(mx, 2, 64));
            mx = fmaxf(mx, __shfl_xor(mx, 4, 64));
            mx = fmaxf(mx, __shfl_xor(mx, 8, 64));
            float se = __expf(logit - mx);
            se += __shfl_xor(se, 1, 64);
            se += __shfl_xor(se, 2, 64);
            se += __shfl_xor(se, 4, 64);
            se += __shfl_xor(se, 8, 64);
            float lse = mx + __logf(se);
            if (cls < 10) {
                int img = blockIdx.x * 16 + (lane >> 4) * 4 + i;  // C row = (l>>4)*4+i
                out[(size_t)img * 10 + cls] = logit - lse;
            }
        }
    }
}

extern "C" void kernel_launch(void* const* d_in, const int* in_sizes, int n_in,
                              void* d_out, int out_size, void* d_ws, size_t ws_size,
                              hipStream_t stream) {
    const float* x     = (const float*)d_in[0];
    const float* theta = (const float*)d_in[1];
    const float* r1_w1 = (const float*)d_in[2];
    const float* r1_g1 = (const float*)d_in[3];
    const float* r1_b1 = (const float*)d_in[4];
    const float* r1_w2 = (const float*)d_in[5];
    const float* r1_g2 = (const float*)d_in[6];
    const float* r1_b2 = (const float*)d_in[7];
    const float* r2_w1 = (const float*)d_in[8];
    const float* r2_g1 = (const float*)d_in[9];
    const float* r2_b1 = (const float*)d_in[10];
    const float* r2_w2 = (const float*)d_in[11];
    const float* r2_g2 = (const float*)d_in[12];
    const float* r2_b2 = (const float*)d_in[13];
    const float* fc_w  = (const float*)d_in[14];
    const float* fc_b  = (const float*)d_in[15];
    const float* alpha = (const float*)d_in[16];
    float* out = (float*)d_out;

    double* stats = (double*)d_ws;                       // 16 KB
    float*  qkpad = (float*)((char*)d_ws + 16384);       // 16 floats
    __half* Bpack = (__half*)((char*)d_ws + 16448);      // 28*512 halfs = 28 KB
    __half* bufA  = (__half*)((char*)d_ws + 65536);      // y1 then y3 (tiled)
    __half* bufB  = bufA + (size_t)NTOT;                 // y2 then y4 (tiled)
    __half* bufD  = bufB + (size_t)NTOT;                 // o1 (tiled)
    __half* bufX  = bufD + (size_t)NTOT;                 // x16 (tiled)

    double* s_y1 = stats + 0 * STAGE_DBL;
    double* s_y2 = stats + 1 * STAGE_DBL;
    double* s_y3 = stats + 2 * STAGE_DBL;
    double* s_y4 = stats + 3 * STAGE_DBL;

    hipMemsetAsync(stats, 0, 4 * STAGE_DBL * sizeof(double), stream);
    k_conv_plain<<<CONVBLK, 256, 0, stream>>>(x, r1_w1, bufA, bufX, s_y1,
                                              fc_w, fc_b, theta, alpha,
                                              Bpack, qkpad);
    k_conv_affine<<<CONVBLK, 256, 0, stream>>>(bufA, s_y1, r1_g1, r1_b1, r1_w2, bufB, s_y2);
    k_conv_resid<<<CONVBLK, 256, 0, stream>>>(bufB, bufX, s_y2, r1_g2, r1_b2, r2_w1, bufA, bufD, s_y3);
    k_conv_affine<<<CONVBLK, 256, 0, stream>>>(bufA, s_y3, r2_g1, r2_b1, r2_w2, bufB, s_y4);
    k_head_mfma<<<1024, 256, 0, stream>>>(bufB, bufD, s_y4, r2_g2, r2_b2,
                                          Bpack, qkpad, alpha, out);
}